// Round 7
// baseline (233.397 us; speedup 1.0000x reference)
//
#include <hip/hip_runtime.h>
#include <stdint.h>

typedef uint16_t u16;
typedef uint32_t u32;
typedef __bf16 bf16_t;
typedef __bf16 bf16x8 __attribute__((ext_vector_type(8)));
typedef __bf16 bf16x4 __attribute__((ext_vector_type(4)));
typedef float  f32x4  __attribute__((ext_vector_type(4)));

#define MFMA16(a,b,c) __builtin_amdgcn_mfma_f32_16x16x32_bf16(a,b,c,0,0,0)

static __device__ __forceinline__ u16 f2bf(float f){
  union { bf16_t b; u16 u; } cv; cv.b = (bf16_t)f; return cv.u;
}
static __device__ __forceinline__ u32 pack2(float a, float b){
  return (u32)f2bf(a) | ((u32)f2bf(b) << 16);
}

// ---------------- K0: exp(bias) table [dh+31][h][dw+31] (63*512 f32) ----------------------
__global__ __launch_bounds__(256) void k_bias_setup(
    const float* __restrict__ dist_bias, const float* __restrict__ dir_bias,
    float* __restrict__ ebtab)
{
  int tid = blockIdx.x*256 + threadIdx.x;
  if (tid >= 63*63) return;
  int dhi = tid / 63, dwi = tid % 63;
  int dh = dhi - 31, dw = dwi - 31;
  int r2 = dh*dh + dw*dw;
  int dist = (int)sqrtf((float)r2);
  if (dist > 59) dist = 59;
  int dir;
  if (dh==0 && dw==0)      dir = 0;
  else if (dh==0)          dir = (dw>0) ? 8  : 0;
  else if (dw==0)          dir = (dh>0) ? 12 : 4;
  else if (dh==dw)         dir = (dh>0) ? 10 : 2;
  else if (dh==-dw)        dir = (dh>0) ? 14 : 6;
  else {
    float ang = atan2f((float)dh, (float)dw) + 3.14159265358979323846f;
    int k = (int)floorf(ang * 2.5464790894703254f);
    dir = k & 15;
  }
  for (int h=0; h<8; h++){
    ebtab[dhi*512 + h*64 + dwi] = expf(dist_bias[dist*8+h] + dir_bias[dir*8+h]);
  }
}

// ---------------- K1: fused Q/K/V projection. blockIdx.y selects matrix. ------------------
// C[8192,256] = X @ W^T + b (f32 in, bf16 MFMA, bf16 out), reg-prefetch double-buffered.
// Wsh/Cs union keeps LDS at 35.8KB -> 3 blocks/CU resident in one dispatch round.
__global__ __attribute__((amdgpu_waves_per_eu(3, 3))) __launch_bounds__(256) void k_proj3(
    const float* __restrict__ X,
    const float* __restrict__ Wq, const float* __restrict__ Bq,
    const float* __restrict__ Wk, const float* __restrict__ Bk,
    const float* __restrict__ Wv, const float* __restrict__ Bvv,
    u16* __restrict__ Qo, u16* __restrict__ Ko, u16* __restrict__ Vo,
    float qscale)
{
  const float* W; const float* Bv; u16* Out; float scale; int vt_mode;
  if (blockIdx.y == 0)      { W = Wq; Bv = Bq;  Out = Qo; scale = qscale; vt_mode = 0; }
  else if (blockIdx.y == 1) { W = Wk; Bv = Bk;  Out = Ko; scale = 1.0f;   vt_mode = 0; }
  else                      { W = Wv; Bv = Bvv; Out = Vo; scale = 1.0f;   vt_mode = 1; }

  __shared__ bf16_t Xs[32*40];
  __shared__ __align__(16) char UU[33280];   // union: Wsh bf16[256*40]=20480B | Cs f32[32*260]=33280B
  bf16_t* Wsh = (bf16_t*)UU;
  float*  Cs  = (float*)UU;
  const int t = threadIdx.x;
  const int wv = t>>6, ln = t&15, qd = (t&63)>>4;
  const int wm = wv & 1, wn = wv >> 1;
  const int m0 = blockIdx.x * 32;

  f32x4 z4 = {0.0f,0.0f,0.0f,0.0f};
  f32x4 acc[8];
  #pragma unroll
  for (int i=0;i<8;i++) acc[i] = z4;

  f32x4 XR; f32x4 WR[8];
  XR = *(const f32x4*)(X + (size_t)(m0 + (t>>3))*256 + (t&7)*4);
  #pragma unroll
  for (int j=0;j<8;j++)
    WR[j] = *(const f32x4*)(W + (size_t)((t>>3)+32*j)*256 + (t&7)*4);

  for (int kt=0; kt<8; kt++){
    __syncthreads();
    { int m = t>>3, k0 = (t&7)*4;
      uint2 pk; pk.x = pack2(XR[0], XR[1]); pk.y = pack2(XR[2], XR[3]);
      *(uint2*)&Xs[m*40 + k0] = pk;
    }
    #pragma unroll
    for (int j=0;j<8;j++){
      int n = (t>>3) + 32*j, k0 = (t&7)*4;
      uint2 pk; pk.x = pack2(WR[j][0], WR[j][1]); pk.y = pack2(WR[j][2], WR[j][3]);
      *(uint2*)&Wsh[n*40 + k0] = pk;
    }
    __syncthreads();
    if (kt < 7){
      XR = *(const f32x4*)(X + (size_t)(m0 + (t>>3))*256 + (kt+1)*32 + (t&7)*4);
      #pragma unroll
      for (int j=0;j<8;j++)
        WR[j] = *(const f32x4*)(W + (size_t)((t>>3)+32*j)*256 + (kt+1)*32 + (t&7)*4);
    }
    bf16x8 a = *(const bf16x8*)&Xs[(wm*16+ln)*40 + qd*8];
    #pragma unroll
    for (int ni=0;ni<8;ni++){
      bf16x8 bb = *(const bf16x8*)&Wsh[(wn*128 + ni*16 + ln)*40 + qd*8];
      acc[ni] = MFMA16(a, bb, acc[ni]);
    }
  }
  __syncthreads();   // Wsh dead after this point; Cs takes over the union
  #pragma unroll
  for (int ni=0;ni<8;ni++){
    const int col = wn*128 + ni*16 + ln;
    const float bias = Bv[col];
    #pragma unroll
    for (int r=0;r<4;r++){
      Cs[(wm*16 + qd*4 + r)*260 + col] = (acc[ni][r] + bias) * scale;
    }
  }
  __syncthreads();
  if (!vt_mode){
    int row = t>>3, c0 = (t&7)*32;
    u16* op = Out + (size_t)(m0+row)*256 + c0;
    #pragma unroll
    for (int i=0;i<4;i++){
      f32x4 v0 = *(const f32x4*)&Cs[row*260 + c0 + i*8];
      f32x4 v1 = *(const f32x4*)&Cs[row*260 + c0 + i*8 + 4];
      union { u16 h[8]; uint4 v; } pk;
      #pragma unroll
      for (int e=0;e<4;e++){ pk.h[e] = f2bf(v0[e]); pk.h[4+e] = f2bf(v1[e]); }
      *(uint4*)(op + i*8) = pk.v;
    }
  } else {
    const int n = t;
    const int b = m0 >> 10, s0 = m0 & 1023;
    u16* op = Out + (size_t)(b*256 + n)*1024 + s0;
    #pragma unroll
    for (int i=0;i<4;i++){
      union { u16 h[8]; uint4 v; } pk;
      #pragma unroll
      for (int e=0;e<8;e++) pk.h[e] = f2bf(Cs[(i*8+e)*260 + n]);
      *(uint4*)(op + i*8) = pk.v;
    }
  }
}

// ---------------- K2a: attention ctx pass. One head per WAVE (heads split across ---------
// blockIdx.z) -> 1024 blocks = 4 blocks/CU = 2x the resident waves of the fused kernel.
// Computes biased-softmax@V (ctx) + writes plain-softmax inverse denominators to sden.
// No barriers at all; Ps is wave-private LDS for the S^T -> P transpose.
__global__ __attribute__((amdgpu_waves_per_eu(4, 4))) __launch_bounds__(256) void k_attn_ctx(
    const u16* __restrict__ Qg, const u16* __restrict__ Kg,
    const u16* __restrict__ Vtg, const float* __restrict__ ebtab,
    u16* __restrict__ ctx, float* __restrict__ sden)
{
  __shared__ bf16_t Ps[4][16*40];          // 5120 B, wave-private

  const int t  = threadIdx.x;
  const int wv = t >> 6;
  const int ln = t & 15;
  const int qd = (t & 63) >> 4;
  const int lane = t & 63;
  const int b  = blockIdx.y;
  const int qt = blockIdx.x;
  const int h  = blockIdx.z*4 + wv;        // this wave's head
  const int qh_img = qt >> 1;
  const int qw0 = (qt & 1) * 16;

  const u16* Qb  = Qg  + (size_t)(b*1024 + qt*16) * 256;
  const u16* Kb  = Kg  + (size_t)b * 1024 * 256;
  const u16* Vtb = Vtg + (size_t)b * 256 * 1024;

  f32x4 z4 = {0.0f,0.0f,0.0f,0.0f};

  bf16x8 aq = *(const bf16x8*)(Qb + ln*256 + h*32 + qd*8);

  float se[4] = {0,0,0,0}, sb[4] = {0,0,0,0};
  f32x4 oacc[2]; oacc[0]=z4; oacc[1]=z4;

  // current-iteration fragments (registers)
  bf16x8 cK[2], cV[2]; float cE;
  #pragma unroll
  for (int kh=0;kh<2;kh++)
    cK[kh] = *(const bf16x8*)(Kb + (size_t)(kh*16 + ln)*256 + h*32 + qd*8);
  #pragma unroll
  for (int nh=0;nh<2;nh++)
    cV[nh] = *(const bf16x8*)(Vtb + (size_t)(h*32 + nh*16 + ln)*1024 + qd*8);
  cE = ebtab[(size_t)(31 - qh_img)*512 + h*64 + lane];

  #pragma unroll 2
  for (int kt=0; kt<32; kt++){
    bf16x8 nK[2], nV[2]; float nE;
    if (kt < 31){
      #pragma unroll
      for (int kh=0;kh<2;kh++)
        nK[kh] = *(const bf16x8*)(Kb + (size_t)((kt+1)*32 + kh*16 + ln)*256 + h*32 + qd*8);
      #pragma unroll
      for (int nh=0;nh<2;nh++)
        nV[nh] = *(const bf16x8*)(Vtb + (size_t)(h*32 + nh*16 + ln)*1024 + (kt+1)*32 + qd*8);
      nE = ebtab[(size_t)(kt + 1 - qh_img + 31)*512 + h*64 + lane];
    }

    #pragma unroll
    for (int kh=0;kh<2;kh++){
      f32x4 sc = MFMA16(aq, cK[kh], z4);
      #pragma unroll
      for (int r=0;r<4;r++){
        float e  = exp2f(sc[r]);                 // Q pre-scaled by log2e/sqrt(dk)
        int idx = kh*16 + ln - (qw0 + qd*4 + r) + 31;   // dw+31 in [0,62]
        float ebv = __shfl(cE, idx);
        float eb = e * ebv;
        se[r] += e;
        sb[r] += eb;
        Ps[wv][(qd*4+r)*40 + kh*16 + ln] = (bf16_t)eb;   // unnormalized
      }
    }
    // per-wave in-order LDS + alias-visible dependence orders Ps write->read
    bf16x8 ap = *(const bf16x8*)&Ps[wv][ln*40 + qd*8];
    oacc[0] = MFMA16(ap, cV[0], oacc[0]);
    oacc[1] = MFMA16(ap, cV[1], oacc[1]);

    if (kt < 31){
      cE = nE;
      #pragma unroll
      for (int kh=0;kh<2;kh++) cK[kh] = nK[kh];
      #pragma unroll
      for (int nh=0;nh<2;nh++) cV[nh] = nV[nh];
    }
  }

  // reduce denominators across the 16 column-lanes (same qd group)
  float inv_se[4], inv_sb[4];
  #pragma unroll
  for (int r=0;r<4;r++){
    float a = se[r], c = sb[r];
    #pragma unroll
    for (int m=1;m<16;m<<=1){ a += __shfl_xor(a, m, 16); c += __shfl_xor(c, m, 16); }
    inv_se[r] = 1.0f / a;
    inv_sb[r] = 1.0f / c;
  }

  // plain-softmax inverse denominators -> global (for k_attn_aw)
  if (ln == 0){
    #pragma unroll
    for (int r=0;r<4;r++)
      sden[(size_t)(b*8 + h)*1024 + qt*16 + qd*4 + r] = inv_se[r];
  }

  // ctx out (normalize by biased denominator)
  #pragma unroll
  for (int nh=0;nh<2;nh++)
    #pragma unroll
    for (int r=0;r<4;r++)
      ctx[(size_t)(b*1024 + qt*16 + qd*4 + r)*256 + h*32 + nh*16 + ln]
          = f2bf(oacc[nh][r] * inv_sb[r]);
}

// ---------------- K2b: attn_w pass. Fully parallel over kt: grid (64,8,4) = 2048 ---------
// blocks = 8 blocks/CU. Zero LDS; low VGPR (per-head aq/inv loaded inside the loop,
// all L1/L2-hot). Each wave owns 2 kt tiles, sums heads in-register, writes AW.
__global__ __launch_bounds__(256) void k_attn_aw(
    const u16* __restrict__ Qg, const u16* __restrict__ Kg,
    const float* __restrict__ sden, float* __restrict__ AW)
{
  const int t  = threadIdx.x;
  const int wv = t >> 6;
  const int ln = t & 15;
  const int qd = (t & 63) >> 4;
  const int b  = blockIdx.y;
  const int qt = blockIdx.x;
  const int kt0 = blockIdx.z*8 + wv*2;

  const u16* Qb = Qg + (size_t)(b*1024 + qt*16) * 256;
  const u16* Kb = Kg + (size_t)b * 1024 * 256;

  f32x4 z4 = {0.0f,0.0f,0.0f,0.0f};

  float aw0[2][2][4];
  #pragma unroll
  for (int k2=0;k2<2;k2++)
    #pragma unroll
    for (int kh=0;kh<2;kh++)
      #pragma unroll
      for (int r=0;r<4;r++) aw0[k2][kh][r] = 0.0f;

  #pragma unroll
  for (int h=0;h<8;h++){
    bf16x8 aqh = *(const bf16x8*)(Qb + ln*256 + h*32 + qd*8);
    float iv[4];
    #pragma unroll
    for (int r=0;r<4;r++)
      iv[r] = sden[(size_t)(b*8 + h)*1024 + qt*16 + qd*4 + r];
    #pragma unroll
    for (int k2=0;k2<2;k2++){
      #pragma unroll
      for (int kh=0;kh<2;kh++){
        bf16x8 bk = *(const bf16x8*)(Kb + (size_t)((kt0+k2)*32 + kh*16 + ln)*256 + h*32 + qd*8);
        f32x4 sc = MFMA16(aqh, bk, z4);
        #pragma unroll
        for (int r=0;r<4;r++)
          aw0[k2][kh][r] += exp2f(sc[r]) * iv[r];
      }
    }
  }
  #pragma unroll
  for (int k2=0;k2<2;k2++)
    #pragma unroll
    for (int kh=0;kh<2;kh++)
      #pragma unroll
      for (int r=0;r<4;r++)
        AW[(size_t)(b*1024 + qt*16 + qd*4 + r)*1024 + (kt0+k2)*32 + kh*16 + ln]
            = aw0[k2][kh][r] * 0.125f;
}

// ---------------- K3: out = ctx@Wo^T + bo ; y = LN(out + x). f32 out. ---------------------
__global__ __attribute__((amdgpu_waves_per_eu(2, 2))) __launch_bounds__(256) void k_outln(
    const u16* __restrict__ CX, const float* __restrict__ Wo,
    const float* __restrict__ bo, const float* __restrict__ xs,
    const float* __restrict__ lgm, const float* __restrict__ lbt,
    float* __restrict__ Out)
{
  __shared__ bf16_t Cts[32*40];
  __shared__ bf16_t Wsh[256*40];
  __shared__ float  Ys[32*260];
  __shared__ float  parts[2][32][2];
  const int t = threadIdx.x;
  const int wv = t>>6, ln = t&15, qd = (t&63)>>4;
  const int wm = wv & 1, wn = wv >> 1;
  const int m0 = blockIdx.x * 32;

  f32x4 z4 = {0.0f,0.0f,0.0f,0.0f};
  f32x4 acc[8];
  #pragma unroll
  for (int i=0;i<8;i++) acc[i] = z4;

  uint2 CR; f32x4 WR[8];
  CR = *(const uint2*)(CX + (size_t)(m0 + (t>>3))*256 + (t&7)*4);
  #pragma unroll
  for (int j=0;j<8;j++)
    WR[j] = *(const f32x4*)(Wo + (size_t)((t>>3)+32*j)*256 + (t&7)*4);

  for (int kt=0; kt<8; kt++){
    __syncthreads();
    { int m = t>>3, k0 = (t&7)*4;
      *(uint2*)&Cts[m*40 + k0] = CR;
    }
    #pragma unroll
    for (int j=0;j<8;j++){
      int n = (t>>3) + 32*j, k0 = (t&7)*4;
      uint2 pk; pk.x = pack2(WR[j][0], WR[j][1]); pk.y = pack2(WR[j][2], WR[j][3]);
      *(uint2*)&Wsh[n*40 + k0] = pk;
    }
    __syncthreads();
    if (kt < 7){
      CR = *(const uint2*)(CX + (size_t)(m0 + (t>>3))*256 + (kt+1)*32 + (t&7)*4);
      #pragma unroll
      for (int j=0;j<8;j++)
        WR[j] = *(const f32x4*)(Wo + (size_t)((t>>3)+32*j)*256 + (kt+1)*32 + (t&7)*4);
    }
    bf16x8 a = *(const bf16x8*)&Cts[(wm*16+ln)*40 + qd*8];
    #pragma unroll
    for (int ni=0;ni<8;ni++){
      bf16x8 bb = *(const bf16x8*)&Wsh[(wn*128 + ni*16 + ln)*40 + qd*8];
      acc[ni] = MFMA16(a, bb, acc[ni]);
    }
  }

  float psum[4]={0,0,0,0}, psq[4]={0,0,0,0};
  #pragma unroll
  for (int ni=0;ni<8;ni++){
    const int col = wn*128 + ni*16 + ln;
    const float bias = bo[col];
    #pragma unroll
    for (int r=0;r<4;r++){
      const int row = wm*16 + qd*4 + r;
      float y = acc[ni][r] + bias + xs[(size_t)(m0+row)*256 + col];
      acc[ni][r] = y;
      psum[r] += y; psq[r] += y*y;
    }
  }
  #pragma unroll
  for (int r=0;r<4;r++){
    float a1 = psum[r], a2 = psq[r];
    #pragma unroll
    for (int m=1;m<16;m<<=1){ a1 += __shfl_xor(a1,m,16); a2 += __shfl_xor(a2,m,16); }
    if (ln == 0){
      parts[wn][wm*16 + qd*4 + r][0] = a1;
      parts[wn][wm*16 + qd*4 + r][1] = a2;
    }
  }
  __syncthreads();
  #pragma unroll
  for (int r=0;r<4;r++){
    const int row = wm*16 + qd*4 + r;
    float mu  = (parts[0][row][0] + parts[1][row][0]) * 0.00390625f;
    float var = (parts[0][row][1] + parts[1][row][1]) * 0.00390625f - mu*mu;
    float rs = rsqrtf(var + 1e-5f);
    #pragma unroll
    for (int ni=0;ni<8;ni++){
      const int col = wn*128 + ni*16 + ln;
      Ys[row*260 + col] = (acc[ni][r] - mu)*rs*lgm[col] + lbt[col];
    }
  }
  __syncthreads();
  { int row = t>>3, c0 = (t&7)*32;
    float* op = Out + (size_t)(m0+row)*256 + c0;
    #pragma unroll
    for (int i=0;i<8;i++)
      *(f32x4*)(op + 4*i) = *(const f32x4*)&Ys[row*260 + c0 + 4*i];
  }
}

// -----------------------------------------------------------------------------------------
extern "C" void kernel_launch(void* const* d_in, const int* in_sizes, int n_in,
                              void* d_out, int out_size, void* d_ws, size_t ws_size,
                              hipStream_t stream)
{
  const float* x   = (const float*)d_in[0];
  const float* wq  = (const float*)d_in[1];
  const float* bq  = (const float*)d_in[2];
  const float* wk  = (const float*)d_in[3];
  const float* bk  = (const float*)d_in[4];
  const float* wv_ = (const float*)d_in[5];
  const float* bv  = (const float*)d_in[6];
  const float* wo  = (const float*)d_in[7];
  const float* bo  = (const float*)d_in[8];
  const float* lng = (const float*)d_in[9];
  const float* lnb = (const float*)d_in[10];
  const float* dib = (const float*)d_in[11];
  const float* drb = (const float*)d_in[12];

  // ws: ebtab 128K | CX bf16 4MB | Vt bf16 4MB | sden f32 256K = 8.63 MB.
  // d_out f32: y [0, 8MB) ; attn_w [8MB, 41.5MB).
  //   Q bf16 at y bytes [0,4M), K bf16 at y bytes [4M,8M) -> dead before k_outln writes y.
  char*  ws    = (char*)d_ws;
  float* ebtab = (float*)ws;
  u16*   CX    = (u16*)(ws + 131072);
  u16*   Vt    = (u16*)(ws + 131072 + 4194304);
  float* sden  = (float*)(ws + 131072 + 8388608);
  float* y     = (float*)d_out;
  float* aw    = y + 2097152;
  u16*   Q     = (u16*)y;
  u16*   K     = (u16*)((char*)y + 4194304);

  const float qscale = 0.25503486f;   // log2(e)/sqrt(32) folded into Q

  k_bias_setup<<<16, 256, 0, stream>>>(dib, drb, ebtab);
  k_proj3<<<dim3(256, 3), 256, 0, stream>>>(x, wq, bq, wk, bk, wv_, bv, Q, K, Vt, qscale);
  k_attn_ctx<<<dim3(64, 8, 2), 256, 0, stream>>>(Q, K, Vt, ebtab, CX, sden);
  k_attn_aw<<<dim3(64, 8, 4), 256, 0, stream>>>(Q, K, sden, aw);
  k_outln<<<256, 256, 0, stream>>>(CX, wo, bo, x, lng, lnb, y);  // overwrites Q,K (dead)
}